// Round 5
// baseline (337.173 us; speedup 1.0000x reference)
//
#include <hip/hip_runtime.h>
#include <hip/hip_bf16.h>

typedef short bf16x8 __attribute__((ext_vector_type(8)));
typedef float f32x4 __attribute__((ext_vector_type(4)));
typedef unsigned short u16;

#define AS1 __attribute__((address_space(1)))
#define AS3 __attribute__((address_space(3)))

#define DIM     1024
#define INNER   512
#define HEADS   8
#define DHEAD   64
#define BATCH   4
#define NTOK    4096
#define NLAT    1024
#define M_X     (BATCH*NTOK)    // 16384
#define M_MED   (BATCH*NLAT)    // 4096
#define LN_EPS  1e-5f

__device__ __forceinline__ float b2f(u16 h) {
    union { unsigned u; float f; } v; v.u = ((unsigned)h) << 16; return v.f;
}
__device__ __forceinline__ u16 f2b(float f) {
    union { float f; unsigned u; } v; v.f = f;
    unsigned r = v.u + 0x7fff + ((v.u >> 16) & 1);
    return (u16)(r >> 16);
}

// ---------------- dtype detection ----------------
__launch_bounds__(256)
__global__ void detect_kernel(const unsigned* __restrict__ xw, const unsigned* __restrict__ maskw,
                              unsigned* __restrict__ flags) {
    __shared__ int s_bad, s_byte;
    if (threadIdx.x == 0) { s_bad = 0; s_byte = 0; }
    __syncthreads();
    unsigned w = xw[threadIdx.x];
    int bad = 0;
    #pragma unroll
    for (int h = 0; h < 2; h++) {
        unsigned el = (h ? (w >> 16) : w) & 0xFFFFu;
        unsigned ef = (el >> 7) & 0xFFu;
        if (!((ef >= 64u && ef < 192u) || (el & 0x7FFFu) == 0u)) bad = 1;
    }
    if (bad) atomicOr(&s_bad, 1);
    for (int i = threadIdx.x; i < NLAT; i += 256)
        if (maskw[i] > 1u) { atomicOr(&s_byte, 1); break; }
    __syncthreads();
    if (threadIdx.x == 0) { flags[0] = s_bad ? 0u : 1u; flags[1] = s_byte ? 1u : 0u; }
}

// ---------------- fused prep: LN + media/mask convert + 3 weight transposes ----------------
// region layout by blockIdx.x:
//   [0, 16384)      LN rows
//   [16384, 18432)  media -> bf16
//   [18432, 18448)  mask -> int32
//   [18448, 18960)  Wq^T  (16 x 32)
//   [18960, 19984)  Wkv^T (32 x 32)
//   [19984, 20496)  Wout^T(32 x 16)
#define PREP_BLOCKS 20496

__device__ __forceinline__ void do_transpose(const void* in, u16* out, int R, int C,
                                             int bx, int by, bool bf, u16 (*t)[33]) {
    int c0 = bx * 32, r0 = by * 32;
    int tid = threadIdx.x;
    int r = tid >> 3, cb = (tid & 7) * 4;
    size_t base = (size_t)(r0 + r) * C + c0 + cb;
    u16 e0, e1, e2, e3;
    if (bf) {
        ushort4 a = *(const ushort4*)((const u16*)in + base);
        e0 = a.x; e1 = a.y; e2 = a.z; e3 = a.w;
    } else {
        float4 a = *(const float4*)((const float*)in + base);
        e0 = f2b(a.x); e1 = f2b(a.y); e2 = f2b(a.z); e3 = f2b(a.w);
    }
    t[r][cb] = e0; t[r][cb + 1] = e1; t[r][cb + 2] = e2; t[r][cb + 3] = e3;
    __syncthreads();
    ushort4 o;
    o.x = t[cb + 0][r]; o.y = t[cb + 1][r]; o.z = t[cb + 2][r]; o.w = t[cb + 3][r];
    *(ushort4*)(out + (size_t)(c0 + r) * R + r0 + cb) = o;
}

__launch_bounds__(256)
__global__ void prep_kernel(const void* __restrict__ x, const void* __restrict__ g,
                            const void* __restrict__ bt, u16* __restrict__ xn,
                            const void* __restrict__ media, u16* __restrict__ media_c,
                            const void* __restrict__ mask, int* __restrict__ mask_c,
                            const void* __restrict__ Wq, u16* __restrict__ WqT,
                            const void* __restrict__ Wkv, u16* __restrict__ WkvT,
                            const void* __restrict__ Wout, u16* __restrict__ WoutT,
                            const unsigned* __restrict__ flags) {
    __shared__ float ss[4], ss2[4];
    __shared__ u16 t[32][33];
    bool bf = flags[0] != 0;
    int bid = blockIdx.x, tid = threadIdx.x;

    if (bid < 16384) {                       // ---- LayerNorm row ----
        int row = bid;
        float v0, v1, v2, v3;
        if (bf) {
            ushort4 xa = ((const ushort4*)((const u16*)x + (size_t)row * DIM))[tid];
            v0 = b2f(xa.x); v1 = b2f(xa.y); v2 = b2f(xa.z); v3 = b2f(xa.w);
        } else {
            float4 xa = ((const float4*)((const float*)x + (size_t)row * DIM))[tid];
            v0 = xa.x; v1 = xa.y; v2 = xa.z; v3 = xa.w;
        }
        float s = v0 + v1 + v2 + v3;
        float s2 = v0 * v0 + v1 * v1 + v2 * v2 + v3 * v3;
        #pragma unroll
        for (int m = 1; m < 64; m <<= 1) { s += __shfl_xor(s, m); s2 += __shfl_xor(s2, m); }
        int w = tid >> 6;
        if ((tid & 63) == 0) { ss[w] = s; ss2[w] = s2; }
        __syncthreads();
        float S = ss[0] + ss[1] + ss[2] + ss[3];
        float S2 = ss2[0] + ss2[1] + ss2[2] + ss2[3];
        float mu = S * (1.f / DIM);
        float var = S2 * (1.f / DIM) - mu * mu;
        float inv = rsqrtf(fmaxf(var, 0.f) + LN_EPS);
        float g0, g1, g2, g3, b0, b1, b2, b3;
        if (bf) {
            ushort4 ga = ((const ushort4*)g)[tid], ba = ((const ushort4*)bt)[tid];
            g0 = b2f(ga.x); g1 = b2f(ga.y); g2 = b2f(ga.z); g3 = b2f(ga.w);
            b0 = b2f(ba.x); b1 = b2f(ba.y); b2 = b2f(ba.z); b3 = b2f(ba.w);
        } else {
            float4 ga = ((const float4*)g)[tid], ba = ((const float4*)bt)[tid];
            g0 = ga.x; g1 = ga.y; g2 = ga.z; g3 = ga.w;
            b0 = ba.x; b1 = ba.y; b2 = ba.z; b3 = ba.w;
        }
        ushort4 o;
        o.x = f2b((v0 - mu) * inv * g0 + b0);
        o.y = f2b((v1 - mu) * inv * g1 + b1);
        o.z = f2b((v2 - mu) * inv * g2 + b2);
        o.w = f2b((v3 - mu) * inv * g3 + b3);
        ((ushort4*)(xn + (size_t)row * DIM))[tid] = o;
    } else if (bid < 18432) {                // ---- media convert ----
        size_t i = ((size_t)(bid - 16384) * 256 + tid) * 8;
        if (bf) {
            *(bf16x8*)(media_c + i) = *(const bf16x8*)((const u16*)media + i);
        } else {
            const float* s = (const float*)media + i;
            float4 a = *(const float4*)s, b = *(const float4*)(s + 4);
            u16 o[8] = {f2b(a.x), f2b(a.y), f2b(a.z), f2b(a.w),
                        f2b(b.x), f2b(b.y), f2b(b.z), f2b(b.w)};
            *(bf16x8*)(media_c + i) = *(bf16x8*)o;
        }
    } else if (bid < 18448) {                // ---- mask convert ----
        bool bytes = flags[1] != 0;
        int i = (bid - 18432) * 256 + tid;
        mask_c[i] = bytes ? (int)((const unsigned char*)mask)[i] : ((const int*)mask)[i];
    } else if (bid < 18960) {                // ---- Wq^T ----
        int idx = bid - 18448;
        do_transpose(Wq, WqT, DIM, INNER, idx & 15, idx >> 4, bf, t);
    } else if (bid < 19984) {                // ---- Wkv^T ----
        int idx = bid - 18960;
        do_transpose(Wkv, WkvT, DIM, DIM, idx & 31, idx >> 5, bf, t);
    } else {                                 // ---- Wout^T ----
        int idx = bid - 19984;
        do_transpose(Wout, WoutT, INNER, DIM, idx & 31, idx >> 5, bf, t);
    }
}

// ---------------- GEMM 128x128: C[M,N] = A[M,K] @ Bt[N,K]^T * scale ----------------
__launch_bounds__(256, 2)
__global__ void gemm128(const u16* __restrict__ A, const u16* __restrict__ Bt,
                        u16* __restrict__ C, float* __restrict__ Cf, int Ndim, int K,
                        float scale, int mode, u16* __restrict__ vT,
                        const unsigned* __restrict__ flags) {
    __shared__ __align__(16) u16 As[128 * 32];
    __shared__ __align__(16) u16 Bs[128 * 32];
    bool outbf = (mode != 2) || (flags[0] != 0);
    int n0 = blockIdx.x * 128, m0 = blockIdx.y * 128;
    int tid = threadIdx.x;
    int w = tid >> 6, lane = tid & 63, quad = lane >> 4, l15 = lane & 15;
    int wm = (w >> 1) * 64, wn = (w & 1) * 64;
    f32x4 acc[4][4] = {};
    int colB = (lane & 3) * 8;
    int rowInSeg = lane >> 2;
    for (int k0 = 0; k0 < K; k0 += 32) {
        __syncthreads();
        #pragma unroll
        for (int i = 0; i < 2; i++) {
            int seg = w * 2 + i;
            int row = seg * 16 + rowInSeg;
            __builtin_amdgcn_global_load_lds(
                (const AS1 void*)(A + (size_t)(m0 + row) * K + k0 + colB),
                (AS3 void*)(As + seg * 512), 16, 0, 0);
            __builtin_amdgcn_global_load_lds(
                (const AS1 void*)(Bt + (size_t)(n0 + row) * K + k0 + colB),
                (AS3 void*)(Bs + seg * 512), 16, 0, 0);
        }
        __syncthreads();
        bf16x8 af[4], bfr[4];
        #pragma unroll
        for (int i = 0; i < 4; i++)
            af[i] = *(bf16x8*)&As[(wm + i * 16 + l15) * 32 + quad * 8];
        #pragma unroll
        for (int j = 0; j < 4; j++)
            bfr[j] = *(bf16x8*)&Bs[(wn + j * 16 + l15) * 32 + quad * 8];
        #pragma unroll
        for (int i = 0; i < 4; i++)
            #pragma unroll
            for (int j = 0; j < 4; j++)
                acc[i][j] = __builtin_amdgcn_mfma_f32_16x16x32_bf16(af[i], bfr[j], acc[i][j], 0, 0, 0);
    }
    #pragma unroll
    for (int i = 0; i < 4; i++)
        #pragma unroll
        for (int j = 0; j < 4; j++)
            #pragma unroll
            for (int r = 0; r < 4; r++) {
                int row = m0 + wm + i * 16 + quad * 4 + r;
                int col = n0 + wn + j * 16 + l15;
                float val = acc[i][j][r] * scale;
                if (mode == 1) {
                    if (col < INNER) {
                        C[(size_t)row * INNER + col] = f2b(val);
                    } else {
                        int c = col - INNER;
                        int h = c >> 6, d = c & 63;
                        int b = row >> 10, jj = row & 1023;
                        vT[(((size_t)(b * HEADS + h) * 64 + d) << 10) + jj] = f2b(val);
                    }
                } else if (outbf) {
                    C[(size_t)row * Ndim + col] = f2b(val);
                } else {
                    Cf[(size_t)row * Ndim + col] = val;
                }
            }
}

// ---------------- Flash attention v3b: KV tiles of 64, DMA staging (8 segs!), padded Ps ----------------
__launch_bounds__(256, 4)
__global__ void flash_kernel(const u16* __restrict__ q, const u16* __restrict__ Kbuf,
                             const u16* __restrict__ vT, const int* __restrict__ mask,
                             u16* __restrict__ attn_out) {
    __shared__ __align__(16) u16 Ks[64 * 64];        // rows j, cols d — 8 DMA segments of 8 rows
    __shared__ __align__(16) u16 Vts[64 * 64];       // rows d, cols j
    __shared__ __align__(16) u16 Ps[4][16 * 68];     // per-wave, stride 68: conflict-free b16 writes
    int bh = blockIdx.x >> 6;
    int qt = blockIdx.x & 63;
    int b = bh >> 3, h = bh & 7;
    int tid = threadIdx.x, w = tid >> 6, lane = tid & 63, quad = lane >> 4, l15 = lane & 15;
    int qrow0 = qt * 64 + w * 16;

    size_t qbase = ((size_t)(b * NTOK) + qrow0 + l15) * INNER + h * 64;
    bf16x8 qf[2];
    qf[0] = *(const bf16x8*)(q + qbase + quad * 8);
    qf[1] = *(const bf16x8*)(q + qbase + 32 + quad * 8);

    f32x4 Oacc[4] = {};
    float lsum[4] = {0.f, 0.f, 0.f, 0.f};
    const int* maskb = mask + b * NLAT;
    int ld_row = lane >> 3, ld_col = (lane & 7) * 8;    // one instr = 8 rows x 64 cols

    for (int jt = 0; jt < NLAT; jt += 64) {
        __syncthreads();
        #pragma unroll
        for (int i = 0; i < 2; i++) {
            int seg = w * 2 + i;                         // 8 segments total (64 rows)
            int j = jt + seg * 8 + ld_row;
            __builtin_amdgcn_global_load_lds(
                (const AS1 void*)(Kbuf + ((size_t)(b * NLAT) + j) * INNER + h * 64 + ld_col),
                (AS3 void*)(Ks + seg * 512), 16, 0, 0);
            int d = seg * 8 + ld_row;
            __builtin_amdgcn_global_load_lds(
                (const AS1 void*)(vT + (((size_t)(b * HEADS + h) * 64 + d) << 10) + jt + ld_col),
                (AS3 void*)(Vts + seg * 512), 16, 0, 0);
        }
        __syncthreads();

        f32x4 S[4];
        #pragma unroll
        for (int c = 0; c < 4; c++) {
            bf16x8 kf0 = *(bf16x8*)&Ks[(c * 16 + l15) * 64 + quad * 8];
            bf16x8 kf1 = *(bf16x8*)&Ks[(c * 16 + l15) * 64 + 32 + quad * 8];
            f32x4 s = {};
            s = __builtin_amdgcn_mfma_f32_16x16x32_bf16(qf[0], kf0, s, 0, 0, 0);
            s = __builtin_amdgcn_mfma_f32_16x16x32_bf16(qf[1], kf1, s, 0, 0, 0);
            S[c] = s;
        }
        int mk[4];
        #pragma unroll
        for (int c = 0; c < 4; c++) mk[c] = maskb[jt + c * 16 + l15];

        #pragma unroll
        for (int c = 0; c < 4; c++)
            #pragma unroll
            for (int r = 0; r < 4; r++) {
                float p = mk[c] ? __expf(fminf(S[c][r], 80.f)) : 0.f;
                lsum[r] += p;
                Ps[w][(quad * 4 + r) * 68 + c * 16 + l15] = f2b(p);
            }
        asm volatile("s_waitcnt lgkmcnt(0)" ::: "memory");   // Ps[w] is wave-private
        bf16x8 pf0 = *(bf16x8*)&Ps[w][l15 * 68 + quad * 8];
        bf16x8 pf1 = *(bf16x8*)&Ps[w][l15 * 68 + 32 + quad * 8];
        #pragma unroll
        for (int dt = 0; dt < 4; dt++) {
            bf16x8 vf0 = *(bf16x8*)&Vts[(dt * 16 + l15) * 64 + quad * 8];
            bf16x8 vf1 = *(bf16x8*)&Vts[(dt * 16 + l15) * 64 + 32 + quad * 8];
            Oacc[dt] = __builtin_amdgcn_mfma_f32_16x16x32_bf16(pf0, vf0, Oacc[dt], 0, 0, 0);
            Oacc[dt] = __builtin_amdgcn_mfma_f32_16x16x32_bf16(pf1, vf1, Oacc[dt], 0, 0, 0);
        }
    }
    #pragma unroll
    for (int r = 0; r < 4; r++) {
        float l = lsum[r];
        l += __shfl_xor(l, 1);
        l += __shfl_xor(l, 2);
        l += __shfl_xor(l, 4);
        l += __shfl_xor(l, 8);
        float invl = (l > 0.f) ? (1.f / l) : 0.f;
        #pragma unroll
        for (int dt = 0; dt < 4; dt++) {
            int row = qrow0 + quad * 4 + r;
            int col = h * 64 + dt * 16 + l15;
            attn_out[(size_t)(b * NTOK + row) * INNER + col] = f2b(Oacc[dt][r] * invl);
        }
    }
}

extern "C" void kernel_launch(void* const* d_in, const int* in_sizes, int n_in,
                              void* d_out, int out_size, void* d_ws, size_t ws_size,
                              hipStream_t stream) {
    const void* x     = d_in[0];
    const void* media = d_in[1];
    const void* mask  = d_in[2];
    const void* g     = d_in[3];
    const void* beta  = d_in[4];
    const void* Wq    = d_in[5];
    const void* Wkv   = d_in[6];
    const void* Wout  = d_in[7];

    char* ws = (char*)d_ws;
    unsigned* flags = (unsigned*)ws;   ws += 256;
    int* mask_c = (int*)ws;            ws += (size_t)M_MED * 4;
    u16* media_c = (u16*)ws;           ws += (size_t)M_MED * DIM * 2;
    u16* xn    = (u16*)ws;             ws += (size_t)M_X * DIM * 2;
    u16* qb    = (u16*)ws;             ws += (size_t)M_X * INNER * 2;
    u16* Kb    = (u16*)ws;             ws += (size_t)M_MED * INNER * 2;
    u16* vTb   = (u16*)ws;             ws += (size_t)M_MED * INNER * 2;
    u16* ao    = (u16*)ws;             ws += (size_t)M_X * INNER * 2;
    u16* WqT   = (u16*)ws;             ws += (size_t)DIM * INNER * 2;
    u16* WkvT  = (u16*)ws;             ws += (size_t)DIM * DIM * 2;
    u16* WoutT = (u16*)ws;             ws += (size_t)INNER * DIM * 2;

    detect_kernel<<<1, 256, 0, stream>>>((const unsigned*)x, (const unsigned*)mask, flags);
    prep_kernel<<<PREP_BLOCKS, 256, 0, stream>>>(x, g, beta, xn, media, media_c, mask, mask_c,
                                                 Wq, WqT, Wkv, WkvT, Wout, WoutT, flags);
    // q = LN(x) @ Wq * 1/sqrt(64)
    gemm128<<<dim3(INNER / 128, M_X / 128), 256, 0, stream>>>(xn, WqT, qb, (float*)nullptr, INNER, DIM,
                                                              0.125f, 0, (u16*)nullptr, flags);
    // kv = media @ Wkv, split into K and V^T
    gemm128<<<dim3(DIM / 128, M_MED / 128), 256, 0, stream>>>(media_c, WkvT, Kb, (float*)nullptr, DIM, DIM,
                                                              1.0f, 1, vTb, flags);
    // masked flash attention
    flash_kernel<<<dim3(32 * 64), 256, 0, stream>>>(qb, Kb, vTb, mask_c, ao);
    // out = attn_out @ Wout (dtype follows flags)
    gemm128<<<dim3(DIM / 128, M_X / 128), 256, 0, stream>>>(ao, WoutT, (u16*)d_out, (float*)d_out, DIM, INNER,
                                                            1.0f, 2, (u16*)nullptr, flags);
}

// Round 6
// 290.031 us; speedup vs baseline: 1.1625x; 1.1625x over previous
//
#include <hip/hip_runtime.h>
#include <hip/hip_bf16.h>

typedef short bf16x8 __attribute__((ext_vector_type(8)));
typedef float f32x4 __attribute__((ext_vector_type(4)));
typedef unsigned short u16;

#define AS1 __attribute__((address_space(1)))
#define AS3 __attribute__((address_space(3)))

#define DIM     1024
#define INNER   512
#define HEADS   8
#define DHEAD   64
#define BATCH   4
#define NTOK    4096
#define NLAT    1024
#define M_X     (BATCH*NTOK)    // 16384
#define M_MED   (BATCH*NLAT)    // 4096
#define LN_EPS  1e-5f

__device__ __forceinline__ float b2f(u16 h) {
    union { unsigned u; float f; } v; v.u = ((unsigned)h) << 16; return v.f;
}
__device__ __forceinline__ u16 f2b(float f) {
    union { float f; unsigned u; } v; v.f = f;
    unsigned r = v.u + 0x7fff + ((v.u >> 16) & 1);
    return (u16)(r >> 16);
}

// ---------------- dtype detection ----------------
__launch_bounds__(256)
__global__ void detect_kernel(const unsigned* __restrict__ xw, const unsigned* __restrict__ maskw,
                              unsigned* __restrict__ flags) {
    __shared__ int s_bad, s_byte;
    if (threadIdx.x == 0) { s_bad = 0; s_byte = 0; }
    __syncthreads();
    unsigned w = xw[threadIdx.x];
    int bad = 0;
    #pragma unroll
    for (int h = 0; h < 2; h++) {
        unsigned el = (h ? (w >> 16) : w) & 0xFFFFu;
        unsigned ef = (el >> 7) & 0xFFu;
        if (!((ef >= 64u && ef < 192u) || (el & 0x7FFFu) == 0u)) bad = 1;
    }
    if (bad) atomicOr(&s_bad, 1);
    for (int i = threadIdx.x; i < NLAT; i += 256)
        if (maskw[i] > 1u) { atomicOr(&s_byte, 1); break; }
    __syncthreads();
    if (threadIdx.x == 0) { flags[0] = s_bad ? 0u : 1u; flags[1] = s_byte ? 1u : 0u; }
}

// ---------------- fused prep: LN + media convert + mask scan + 3 weight transposes ----------------
// region layout by blockIdx.x:
//   [0, 16384)      LN rows
//   [16384, 18432)  media -> bf16
//   [18432, 18436)  mask scan: map[b][j] -> compact slot (-1 if masked), cnt[b]
//   [18436, 18948)  Wq^T  (16 x 32)
//   [18948, 19972)  Wkv^T (32 x 32)
//   [19972, 20484)  Wout^T(32 x 16)
#define PREP_BLOCKS 20484

__device__ __forceinline__ void do_transpose(const void* in, u16* out, int R, int C,
                                             int bx, int by, bool bf, u16 (*t)[33]) {
    int c0 = bx * 32, r0 = by * 32;
    int tid = threadIdx.x;
    int r = tid >> 3, cb = (tid & 7) * 4;
    size_t base = (size_t)(r0 + r) * C + c0 + cb;
    u16 e0, e1, e2, e3;
    if (bf) {
        ushort4 a = *(const ushort4*)((const u16*)in + base);
        e0 = a.x; e1 = a.y; e2 = a.z; e3 = a.w;
    } else {
        float4 a = *(const float4*)((const float*)in + base);
        e0 = f2b(a.x); e1 = f2b(a.y); e2 = f2b(a.z); e3 = f2b(a.w);
    }
    t[r][cb] = e0; t[r][cb + 1] = e1; t[r][cb + 2] = e2; t[r][cb + 3] = e3;
    __syncthreads();
    ushort4 o;
    o.x = t[cb + 0][r]; o.y = t[cb + 1][r]; o.z = t[cb + 2][r]; o.w = t[cb + 3][r];
    *(ushort4*)(out + (size_t)(c0 + r) * R + r0 + cb) = o;
}

__launch_bounds__(256)
__global__ void prep_kernel(const void* __restrict__ x, const void* __restrict__ g,
                            const void* __restrict__ bt, u16* __restrict__ xn,
                            const void* __restrict__ media, u16* __restrict__ media_c,
                            const void* __restrict__ mask, int* __restrict__ map,
                            int* __restrict__ cnt,
                            const void* __restrict__ Wq, u16* __restrict__ WqT,
                            const void* __restrict__ Wkv, u16* __restrict__ WkvT,
                            const void* __restrict__ Wout, u16* __restrict__ WoutT,
                            const unsigned* __restrict__ flags) {
    __shared__ float ss[4], ss2[4];
    __shared__ int wsumI[4];
    __shared__ u16 t[32][33];
    bool bf = flags[0] != 0;
    int bid = blockIdx.x, tid = threadIdx.x;

    if (bid < 16384) {                       // ---- LayerNorm row ----
        int row = bid;
        float v0, v1, v2, v3;
        if (bf) {
            ushort4 xa = ((const ushort4*)((const u16*)x + (size_t)row * DIM))[tid];
            v0 = b2f(xa.x); v1 = b2f(xa.y); v2 = b2f(xa.z); v3 = b2f(xa.w);
        } else {
            float4 xa = ((const float4*)((const float*)x + (size_t)row * DIM))[tid];
            v0 = xa.x; v1 = xa.y; v2 = xa.z; v3 = xa.w;
        }
        float s = v0 + v1 + v2 + v3;
        float s2 = v0 * v0 + v1 * v1 + v2 * v2 + v3 * v3;
        #pragma unroll
        for (int m = 1; m < 64; m <<= 1) { s += __shfl_xor(s, m); s2 += __shfl_xor(s2, m); }
        int w = tid >> 6;
        if ((tid & 63) == 0) { ss[w] = s; ss2[w] = s2; }
        __syncthreads();
        float S = ss[0] + ss[1] + ss[2] + ss[3];
        float S2 = ss2[0] + ss2[1] + ss2[2] + ss2[3];
        float mu = S * (1.f / DIM);
        float var = S2 * (1.f / DIM) - mu * mu;
        float inv = rsqrtf(fmaxf(var, 0.f) + LN_EPS);
        float g0, g1, g2, g3, b0, b1, b2, b3;
        if (bf) {
            ushort4 ga = ((const ushort4*)g)[tid], ba = ((const ushort4*)bt)[tid];
            g0 = b2f(ga.x); g1 = b2f(ga.y); g2 = b2f(ga.z); g3 = b2f(ga.w);
            b0 = b2f(ba.x); b1 = b2f(ba.y); b2 = b2f(ba.z); b3 = b2f(ba.w);
        } else {
            float4 ga = ((const float4*)g)[tid], ba = ((const float4*)bt)[tid];
            g0 = ga.x; g1 = ga.y; g2 = ga.z; g3 = ga.w;
            b0 = ba.x; b1 = ba.y; b2 = ba.z; b3 = ba.w;
        }
        ushort4 o;
        o.x = f2b((v0 - mu) * inv * g0 + b0);
        o.y = f2b((v1 - mu) * inv * g1 + b1);
        o.z = f2b((v2 - mu) * inv * g2 + b2);
        o.w = f2b((v3 - mu) * inv * g3 + b3);
        ((ushort4*)(xn + (size_t)row * DIM))[tid] = o;
    } else if (bid < 18432) {                // ---- media convert ----
        size_t i = ((size_t)(bid - 16384) * 256 + tid) * 8;
        if (bf) {
            *(bf16x8*)(media_c + i) = *(const bf16x8*)((const u16*)media + i);
        } else {
            const float* s = (const float*)media + i;
            float4 a = *(const float4*)s, b = *(const float4*)(s + 4);
            u16 o[8] = {f2b(a.x), f2b(a.y), f2b(a.z), f2b(a.w),
                        f2b(b.x), f2b(b.y), f2b(b.z), f2b(b.w)};
            *(bf16x8*)(media_c + i) = *(bf16x8*)o;
        }
    } else if (bid < 18436) {                // ---- mask scan (one block per batch) ----
        int b = bid - 18432;
        bool bytes = flags[1] != 0;
        int v[4];
        if (bytes) {
            unsigned wd = ((const unsigned*)mask)[b * 256 + tid];
            #pragma unroll
            for (int i = 0; i < 4; i++) v[i] = ((wd >> (8 * i)) & 0xFFu) ? 1 : 0;
        } else {
            int4 m4 = ((const int4*)mask)[b * 256 + tid];
            v[0] = m4.x != 0; v[1] = m4.y != 0; v[2] = m4.z != 0; v[3] = m4.w != 0;
        }
        int tsum = v[0] + v[1] + v[2] + v[3];
        int lane = tid & 63, w = tid >> 6;
        int incl = tsum;
        #pragma unroll
        for (int off = 1; off < 64; off <<= 1) {
            int tt = __shfl_up(incl, off);
            if (lane >= off) incl += tt;
        }
        if (lane == 63) wsumI[w] = incl;
        __syncthreads();
        int base = 0;
        for (int k = 0; k < w; k++) base += wsumI[k];
        int slot = base + incl - tsum;
        int gbase = b * NLAT + tid * 4;
        #pragma unroll
        for (int i = 0; i < 4; i++) map[gbase + i] = v[i] ? slot++ : -1;
        if (tid == 0) cnt[b] = wsumI[0] + wsumI[1] + wsumI[2] + wsumI[3];
    } else if (bid < 18948) {                // ---- Wq^T ----
        int idx = bid - 18436;
        do_transpose(Wq, WqT, DIM, INNER, idx & 15, idx >> 4, bf, t);
    } else if (bid < 19972) {                // ---- Wkv^T ----
        int idx = bid - 18948;
        do_transpose(Wkv, WkvT, DIM, DIM, idx & 31, idx >> 5, bf, t);
    } else {                                 // ---- Wout^T ----
        int idx = bid - 19972;
        do_transpose(Wout, WoutT, INNER, DIM, idx & 31, idx >> 5, bf, t);
    }
}

// ---------------- GEMM 128x128, XOR-swizzled LDS: C = A @ Bt^T * scale ----------------
// Swizzle: LDS physical colgroup p (8 u16) at row r holds logical group p ^ ((r>>1)&3).
__launch_bounds__(256, 2)
__global__ void gemm128(const u16* __restrict__ A, const u16* __restrict__ Bt,
                        u16* __restrict__ C, float* __restrict__ Cf, int Ndim, int K,
                        float scale, int mode, u16* __restrict__ vT,
                        const int* __restrict__ map,
                        const unsigned* __restrict__ flags) {
    __shared__ __align__(16) u16 As[128 * 32];
    __shared__ __align__(16) u16 Bs[128 * 32];
    bool outbf = (mode != 2) || (flags[0] != 0);
    int n0 = blockIdx.x * 128, m0 = blockIdx.y * 128;
    int tid = threadIdx.x;
    int w = tid >> 6, lane = tid & 63, quad = lane >> 4, l15 = lane & 15;
    int wm = (w >> 1) * 64, wn = (w & 1) * 64;
    f32x4 acc[4][4] = {};
    int rowInSeg = lane >> 2;
    int colB = (((lane & 3) ^ ((lane >> 3) & 3))) * 8;   // swizzled source colgroup
    for (int k0 = 0; k0 < K; k0 += 32) {
        __syncthreads();
        #pragma unroll
        for (int i = 0; i < 2; i++) {
            int seg = w * 2 + i;
            int row = seg * 16 + rowInSeg;
            __builtin_amdgcn_global_load_lds(
                (const AS1 void*)(A + (size_t)(m0 + row) * K + k0 + colB),
                (AS3 void*)(As + seg * 512), 16, 0, 0);
            __builtin_amdgcn_global_load_lds(
                (const AS1 void*)(Bt + (size_t)(n0 + row) * K + k0 + colB),
                (AS3 void*)(Bs + seg * 512), 16, 0, 0);
        }
        __syncthreads();
        int sw = quad ^ ((l15 >> 1) & 3);                 // swizzled read colgroup
        bf16x8 af[4], bfr[4];
        #pragma unroll
        for (int i = 0; i < 4; i++)
            af[i] = *(bf16x8*)&As[(wm + i * 16 + l15) * 32 + sw * 8];
        #pragma unroll
        for (int j = 0; j < 4; j++)
            bfr[j] = *(bf16x8*)&Bs[(wn + j * 16 + l15) * 32 + sw * 8];
        #pragma unroll
        for (int i = 0; i < 4; i++)
            #pragma unroll
            for (int j = 0; j < 4; j++)
                acc[i][j] = __builtin_amdgcn_mfma_f32_16x16x32_bf16(af[i], bfr[j], acc[i][j], 0, 0, 0);
    }
    #pragma unroll
    for (int i = 0; i < 4; i++)
        #pragma unroll
        for (int j = 0; j < 4; j++)
            #pragma unroll
            for (int r = 0; r < 4; r++) {
                int row = m0 + wm + i * 16 + quad * 4 + r;
                int col = n0 + wn + j * 16 + l15;
                float val = acc[i][j][r] * scale;
                if (mode == 1) {
                    int b = row >> 10, jj = row & 1023;
                    int slot = map[(b << 10) + jj];
                    if (slot >= 0) {
                        if (col < INNER) {
                            C[((size_t)(b << 10) + slot) * INNER + col] = f2b(val);
                        } else {
                            int c = col - INNER;
                            int h = c >> 6, d = c & 63;
                            vT[(((size_t)(b * HEADS + h) * 64 + d) << 10) + slot] = f2b(val);
                        }
                    }
                } else if (outbf) {
                    C[(size_t)row * Ndim + col] = f2b(val);
                } else {
                    Cf[(size_t)row * Ndim + col] = val;
                }
            }
}

// ---------------- Flash attention v4: compacted KV, swizzled DMA staging ----------------
__launch_bounds__(256, 4)
__global__ void flash_kernel(const u16* __restrict__ q, const u16* __restrict__ Kc,
                             const u16* __restrict__ vTc, const int* __restrict__ cntp,
                             u16* __restrict__ attn_out) {
    __shared__ __align__(16) u16 Ks[64 * 64];        // physical colgroup p = logical ^ (row&7)
    __shared__ __align__(16) u16 Vts[64 * 64];
    __shared__ __align__(16) u16 Ps[4][16 * 68];     // per-wave, stride 68: conflict-free
    int bh = blockIdx.x >> 6;
    int qt = blockIdx.x & 63;
    int b = bh >> 3, h = bh & 7;
    int tid = threadIdx.x, w = tid >> 6, lane = tid & 63, quad = lane >> 4, l15 = lane & 15;
    int qrow0 = qt * 64 + w * 16;
    int cnt = cntp[b];

    size_t qbase = ((size_t)(b * NTOK) + qrow0 + l15) * INNER + h * 64;
    bf16x8 qf[2];
    qf[0] = *(const bf16x8*)(q + qbase + quad * 8);
    qf[1] = *(const bf16x8*)(q + qbase + 32 + quad * 8);

    f32x4 Oacc[4] = {};
    float lsum[4] = {0.f, 0.f, 0.f, 0.f};
    int ld_row = lane >> 3;
    int ld_col = ((lane & 7) ^ ld_row) * 8;          // swizzled source colgroup

    for (int jt = 0; jt < cnt; jt += 64) {
        __syncthreads();
        #pragma unroll
        for (int i = 0; i < 2; i++) {
            int seg = w * 2 + i;                     // 8 segments = 64 rows
            int j = jt + seg * 8 + ld_row;
            __builtin_amdgcn_global_load_lds(
                (const AS1 void*)(Kc + ((size_t)(b * NLAT) + j) * INNER + h * 64 + ld_col),
                (AS3 void*)(Ks + seg * 512), 16, 0, 0);
            int d = seg * 8 + ld_row;
            __builtin_amdgcn_global_load_lds(
                (const AS1 void*)(vTc + (((size_t)(b * HEADS + h) * 64 + d) << 10) + jt + ld_col),
                (AS3 void*)(Vts + seg * 512), 16, 0, 0);
        }
        __syncthreads();

        int sw0 = (quad ^ (l15 & 7)) * 8;            // logical groups quad / quad+4
        int sw1 = ((quad + 4) ^ (l15 & 7)) * 8;
        f32x4 S[4];
        #pragma unroll
        for (int c = 0; c < 4; c++) {
            bf16x8 kf0 = *(bf16x8*)&Ks[(c * 16 + l15) * 64 + sw0];
            bf16x8 kf1 = *(bf16x8*)&Ks[(c * 16 + l15) * 64 + sw1];
            f32x4 s = {};
            s = __builtin_amdgcn_mfma_f32_16x16x32_bf16(qf[0], kf0, s, 0, 0, 0);
            s = __builtin_amdgcn_mfma_f32_16x16x32_bf16(qf[1], kf1, s, 0, 0, 0);
            S[c] = s;
        }
        #pragma unroll
        for (int c = 0; c < 4; c++) {
            bool valid = (jt + c * 16 + l15) < cnt;
            #pragma unroll
            for (int r = 0; r < 4; r++) {
                float p = valid ? __expf(fminf(S[c][r], 80.f)) : 0.f;
                lsum[r] += p;
                Ps[w][(quad * 4 + r) * 68 + c * 16 + l15] = f2b(p);
            }
        }
        asm volatile("s_waitcnt lgkmcnt(0)" ::: "memory");   // Ps[w] is wave-private
        bf16x8 pf0 = *(bf16x8*)&Ps[w][l15 * 68 + quad * 8];
        bf16x8 pf1 = *(bf16x8*)&Ps[w][l15 * 68 + 32 + quad * 8];
        #pragma unroll
        for (int dt = 0; dt < 4; dt++) {
            bf16x8 vf0 = *(bf16x8*)&Vts[(dt * 16 + l15) * 64 + sw0];
            bf16x8 vf1 = *(bf16x8*)&Vts[(dt * 16 + l15) * 64 + sw1];
            Oacc[dt] = __builtin_amdgcn_mfma_f32_16x16x32_bf16(pf0, vf0, Oacc[dt], 0, 0, 0);
            Oacc[dt] = __builtin_amdgcn_mfma_f32_16x16x32_bf16(pf1, vf1, Oacc[dt], 0, 0, 0);
        }
    }
    #pragma unroll
    for (int r = 0; r < 4; r++) {
        float l = lsum[r];
        l += __shfl_xor(l, 1);
        l += __shfl_xor(l, 2);
        l += __shfl_xor(l, 4);
        l += __shfl_xor(l, 8);
        float invl = (l > 0.f) ? (1.f / l) : 0.f;
        #pragma unroll
        for (int dt = 0; dt < 4; dt++) {
            int row = qrow0 + quad * 4 + r;
            int col = h * 64 + dt * 16 + l15;
            attn_out[(size_t)(b * NTOK + row) * INNER + col] = f2b(Oacc[dt][r] * invl);
        }
    }
}

extern "C" void kernel_launch(void* const* d_in, const int* in_sizes, int n_in,
                              void* d_out, int out_size, void* d_ws, size_t ws_size,
                              hipStream_t stream) {
    const void* x     = d_in[0];
    const void* media = d_in[1];
    const void* mask  = d_in[2];
    const void* g     = d_in[3];
    const void* beta  = d_in[4];
    const void* Wq    = d_in[5];
    const void* Wkv   = d_in[6];
    const void* Wout  = d_in[7];

    char* ws = (char*)d_ws;
    unsigned* flags = (unsigned*)ws;   ws += 256;
    int* map_c  = (int*)ws;            ws += (size_t)M_MED * 4;
    int* cnt_c  = (int*)ws;            ws += 256;
    u16* media_c = (u16*)ws;           ws += (size_t)M_MED * DIM * 2;
    u16* xn    = (u16*)ws;             ws += (size_t)M_X * DIM * 2;
    u16* qb    = (u16*)ws;             ws += (size_t)M_X * INNER * 2;
    u16* Kb    = (u16*)ws;             ws += (size_t)M_MED * INNER * 2;
    u16* vTb   = (u16*)ws;             ws += (size_t)M_MED * INNER * 2;
    u16* ao    = (u16*)ws;             ws += (size_t)M_X * INNER * 2;
    u16* WqT   = (u16*)ws;             ws += (size_t)DIM * INNER * 2;
    u16* WkvT  = (u16*)ws;             ws += (size_t)DIM * DIM * 2;
    u16* WoutT = (u16*)ws;             ws += (size_t)INNER * DIM * 2;

    detect_kernel<<<1, 256, 0, stream>>>((const unsigned*)x, (const unsigned*)mask, flags);
    prep_kernel<<<PREP_BLOCKS, 256, 0, stream>>>(x, g, beta, xn, media, media_c, mask, map_c, cnt_c,
                                                 Wq, WqT, Wkv, WkvT, Wout, WoutT, flags);
    // q = LN(x) @ Wq * 1/sqrt(64)
    gemm128<<<dim3(INNER / 128, M_X / 128), 256, 0, stream>>>(xn, WqT, qb, (float*)nullptr, INNER, DIM,
                                                              0.125f, 0, (u16*)nullptr, (int*)nullptr, flags);
    // kv = media @ Wkv, epilogue scatters compacted K and V^T via map
    gemm128<<<dim3(DIM / 128, M_MED / 128), 256, 0, stream>>>(media_c, WkvT, Kb, (float*)nullptr, DIM, DIM,
                                                              1.0f, 1, vTb, map_c, flags);
    // masked flash attention over compacted KV
    flash_kernel<<<dim3(32 * 64), 256, 0, stream>>>(qb, Kb, vTb, cnt_c, ao);
    // out = attn_out @ Wout (dtype follows flags)
    gemm128<<<dim3(DIM / 128, M_X / 128), 256, 0, stream>>>(ao, WoutT, (u16*)d_out, (float*)d_out, DIM, INNER,
                                                            1.0f, 2, (u16*)nullptr, (int*)nullptr, flags);
}